// Round 10
// baseline (369.322 us; speedup 1.0000x reference)
//
#include <hip/hip_runtime.h>
#include <hip/hip_bf16.h>

#define NR 12288
#define DIMS 256
#define TOPP 9
#define NCH 8               // main-pass col chunks (1536 cols, chunk == XCD)
#define CWM 1536
#define SMP 1536            // threshold sample width per row (E ~71 survivors)
#define PKT 32768           // bytes per packed 64-col tile

typedef __attribute__((ext_vector_type(8))) short short8v;
typedef __attribute__((ext_vector_type(4))) float f32x4;

__device__ __forceinline__ unsigned short f2bf(float f) {
    unsigned int u = __float_as_uint(f);
    u += 0x7fffu + ((u >> 16) & 1u);
    return (unsigned short)(u >> 16);
}

// Sortable key: top 18 bits = monotone-mapped float, low 14 = col (unique).
__device__ __forceinline__ unsigned packkey(float v, int col) {
    unsigned u = __float_as_uint(v);
    u ^= (unsigned)((int)u >> 31) | 0x80000000u;
    return (u & 0xFFFFC000u) | (unsigned)col;
}

// Keep 9 largest keys; replace-all-equal-mn requires ALL values distinct.
// Sentinels must be lane-unique before any cross-lane merge (round-7 lesson).
__device__ __forceinline__ void top9u(unsigned (&a)[9], unsigned& mn, unsigned key) {
    if (key > mn) {
#pragma unroll
        for (int k = 0; k < 9; ++k) a[k] = (a[k] == mn) ? key : a[k];
        unsigned m = a[0];
#pragma unroll
        for (int k = 1; k < 9; ++k) m = min(m, a[k]);
        mn = m;
    }
}

// async global->LDS DMA, 16B per lane (dest = wave-uniform base + lane*16)
__device__ __forceinline__ void gld16(const void* g, void* l) {
    __builtin_amdgcn_global_load_lds(
        (const __attribute__((address_space(1))) void*)g,
        (__attribute__((address_space(3))) void*)l, 16, 0, 0);
}

// ---------- 1) normalize fp32 -> bf16 directly into packed fragment layout --
// frag addr of (col-row C, kk, lg): (C>>6)*PKT + kk*4096 + (C&63)*64 + lg*16
__global__ void k_normpack(const float* __restrict__ x, char* __restrict__ pk) {
    const int wave = threadIdx.x >> 6, lane = threadIdx.x & 63;
    const int row = blockIdx.x * 4 + wave;
    const float4 v = *(const float4*)(x + (size_t)row * DIMS + lane * 4);
    float ss = v.x * v.x + v.y * v.y + v.z * v.z + v.w * v.w;
#pragma unroll
    for (int off = 32; off > 0; off >>= 1) ss += __shfl_xor(ss, off);
    const float inv = 1.0f / fmaxf(sqrtf(ss), 1e-12f);
    ushort4 o;
    o.x = f2bf(v.x * inv); o.y = f2bf(v.y * inv);
    o.z = f2bf(v.z * inv); o.w = f2bf(v.w * inv);
    const int kk = lane >> 3, lg = (lane >> 1) & 3, sub = (lane & 1) * 8;
    *(ushort4*)(pk + (size_t)(row >> 6) * PKT + kk * 4096 + (row & 63) * 64 + lg * 16 + sub) = o;
}

// ---------- 2) k_thrS: per-row lower-bound threshold from a 1536-col sample --
__global__ __launch_bounds__(256, 4) void k_thrS(const char* __restrict__ pk,
                                                 float* __restrict__ thrF) {
    const int bid = blockIdx.x;
    const int w = threadIdx.x >> 6, lane = threadIdx.x & 63;
    const int l15 = lane & 15, lg = lane >> 4;
    const int R = bid * 16;
    const int base = (bid & 7) * SMP + w * 384;

    short8v aF[8];
    {
        const char* ap = pk + (size_t)(R >> 6) * PKT + ((R & 63) + l15) * 64 + lg * 16;
#pragma unroll
        for (int kk = 0; kk < 8; ++kk) aF[kk] = *(const short8v*)(ap + kk * 4096);
    }
    unsigned t9[4][9]; unsigned kmin[4];
#pragma unroll
    for (int r = 0; r < 4; ++r) {
        kmin[r] = (unsigned)(lane * 16);
#pragma unroll
        for (int k = 0; k < 9; ++k) t9[r][k] = (unsigned)(lane * 16 + k);   // lane-unique
    }

    for (int t = 0; t < 6; ++t) {
        const int cb = base + t * 64;
        const char* tb = pk + (size_t)(cb >> 6) * PKT + l15 * 64 + lg * 16;
        f32x4 acc0 = {0.f,0.f,0.f,0.f}, acc1 = {0.f,0.f,0.f,0.f};
        f32x4 acc2 = {0.f,0.f,0.f,0.f}, acc3 = {0.f,0.f,0.f,0.f};
#pragma unroll
        for (int kk = 0; kk < 8; ++kk) {
            short8v b0 = *(const short8v*)(tb + kk * 4096);
            short8v b1 = *(const short8v*)(tb + kk * 4096 + 1024);
            short8v b2 = *(const short8v*)(tb + kk * 4096 + 2048);
            short8v b3 = *(const short8v*)(tb + kk * 4096 + 3072);
            acc0 = __builtin_amdgcn_mfma_f32_16x16x32_bf16(aF[kk], b0, acc0, 0,0,0);
            acc1 = __builtin_amdgcn_mfma_f32_16x16x32_bf16(aF[kk], b1, acc1, 0,0,0);
            acc2 = __builtin_amdgcn_mfma_f32_16x16x32_bf16(aF[kk], b2, acc2, 0,0,0);
            acc3 = __builtin_amdgcn_mfma_f32_16x16x32_bf16(aF[kk], b3, acc3, 0,0,0);
        }
        const int c0 = cb + l15;
#pragma unroll
        for (int r = 0; r < 4; ++r) {
            top9u(t9[r], kmin[r], packkey(acc0[r], c0));
            top9u(t9[r], kmin[r], packkey(acc1[r], c0 + 16));
            top9u(t9[r], kmin[r], packkey(acc2[r], c0 + 32));
            top9u(t9[r], kmin[r], packkey(acc3[r], c0 + 48));
        }
    }

    // merge over the 16 lanes (cols) sharing each row: snapshot-then-insert
#pragma unroll
    for (int off = 1; off < 16; off <<= 1) {
#pragma unroll
        for (int r = 0; r < 4; ++r) {
            unsigned o[9];
#pragma unroll
            for (int k = 0; k < 9; ++k) o[k] = (unsigned)__shfl_xor((int)t9[r][k], off);
#pragma unroll
            for (int k = 0; k < 9; ++k) top9u(t9[r], kmin[r], o[k]);
        }
    }
    __shared__ unsigned m9[4][16][9];
    if (l15 == 0) {
#pragma unroll
        for (int r = 0; r < 4; ++r)
#pragma unroll
            for (int k = 0; k < 9; ++k) m9[w][lg * 4 + r][k] = t9[r][k];
    }
    __syncthreads();
    if (threadIdx.x < 16) {
        unsigned a[9]; unsigned mn = 0;
#pragma unroll
        for (int k = 0; k < 9; ++k) a[k] = (unsigned)k;   // serial: distinct ok
        for (int ww = 0; ww < 4; ++ww)
#pragma unroll
            for (int k = 0; k < 9; ++k) top9u(a, mn, m9[ww][threadIdx.x][k]);
        // float whose key-floor equals mn's quantum: (v >= tF) <=> key18(v) >= mn&~0x3FFF
        const unsigned T = mn & 0xFFFFC000u;
        thrF[R + threadIdx.x] = (T & 0x80000000u) ? __uint_as_float(T ^ 0x80000000u)
                                                  : __uint_as_float(~T);
    }
}

// ---------- 3) k_mainL: LDS-staged GEMM via global_load_lds, 8 waves ----------
// Rounds 8/9 lesson: >128 live VGPRs gets wrecked by the allocator. This
// design needs ~96: wave = (row-group rg of 32 rows, col-strip cs of 16 cols);
// aF = 64 VGPR; B staged in LDS as a LINEAR copy of the packed tile (packed
// fragment layout is naturally at the b128 bank floor -> no swizzle), DMA'd
// with global_load_lds (zero staging VGPRs/VALU). 2:1 MFMA:ds_read.
__global__ __launch_bounds__(512, 4) void k_mainL(const char* __restrict__ pk,
                                                  const float* __restrict__ thrF,
                                                  unsigned* __restrict__ bufg,
                                                  unsigned* __restrict__ cnt,
                                                  unsigned capc) {
    const int bid = blockIdx.x;
    const int chunk = bid & 7, rb = bid >> 3;     // chunk == XCD id
    const int w = threadIdx.x >> 6, lane = threadIdx.x & 63;
    const int l15 = lane & 15, lg = lane >> 4;
    const int rg = w >> 2, cs = w & 3;
    const int R0 = rb * 64;

    __shared__ __align__(1024) char sb0[PKT];
    __shared__ __align__(1024) char sb1[PKT];

    // A fragments: 32 rows (2 row-tiles) x 256 K from packed global
    short8v aF0[8], aF1[8];
    {
        const char* ap = pk + (size_t)rb * PKT + (rg * 32 + l15) * 64 + lg * 16;
#pragma unroll
        for (int kk = 0; kk < 8; ++kk) {
            aF0[kk] = *(const short8v*)(ap + kk * 4096);
            aF1[kk] = *(const short8v*)(ap + kk * 4096 + 16 * 64);
        }
    }
    float tv0[4], tv1[4];
#pragma unroll
    for (int r = 0; r < 4; ++r) {
        tv0[r] = thrF[R0 + rg * 32 + lg * 4 + r];
        tv1[r] = thrF[R0 + rg * 32 + 16 + lg * 4 + r];
    }

    const int NT = CWM / 64;                      // 24 tiles
    const char* tb0 = pk + (size_t)(chunk * NT) * PKT;

    // prologue: DMA tile 0 into sb0 (8 waves x 4 KB)
    {
        const char* g = tb0 + w * 4096 + lane * 16;
#pragma unroll
        for (int c = 0; c < 4; ++c) gld16(g + c * 1024, sb0 + w * 4096 + c * 1024);
    }
    __syncthreads();

#define APPEND(ACC, TV, ROFF)                                                  \
    _Pragma("unroll")                                                          \
    for (int r = 0; r < 4; ++r) {                                              \
        if (ACC[r] >= TV[r]) {                                                 \
            const int rgl = R0 + rg * 32 + (ROFF) + lg * 4 + r;                \
            const unsigned key = packkey(ACC[r], col);                         \
            const unsigned idx = atomicAdd(&cnt[rgl], 1u);                     \
            if (idx < capc) bufg[(size_t)rgl * capc + idx] = key;              \
        }                                                                      \
    }

    for (int ct = 0; ct < NT; ++ct) {
        char* sbC = (ct & 1) ? sb1 : sb0;
        char* sbN = (ct & 1) ? sb0 : sb1;
        if (ct + 1 < NT) {                        // issue next-tile DMA early
            const char* g = tb0 + (size_t)(ct + 1) * PKT + w * 4096 + lane * 16;
#pragma unroll
            for (int c = 0; c < 4; ++c) gld16(g + c * 1024, sbN + w * 4096 + c * 1024);
        }
        const char* lb = sbC + (cs * 16 + l15) * 64 + lg * 16;
        f32x4 acc0 = {0.f,0.f,0.f,0.f}, acc1 = {0.f,0.f,0.f,0.f};
#pragma unroll
        for (int kk = 0; kk < 8; ++kk) {
            short8v bF = *(const short8v*)(lb + kk * 4096);
            acc0 = __builtin_amdgcn_mfma_f32_16x16x32_bf16(aF0[kk], bF, acc0, 0,0,0);
            acc1 = __builtin_amdgcn_mfma_f32_16x16x32_bf16(aF1[kk], bF, acc1, 0,0,0);
        }
        const int col = chunk * CWM + ct * 64 + cs * 16 + l15;
        APPEND(acc0, tv0, 0)
        APPEND(acc1, tv1, 16)
        __syncthreads();                          // drains DMA (vmcnt) + LDS reads
    }
#undef APPEND
}

// ---------- 4) k_sel: exact per-row 9th key over survivors + degrees ----------
// 16 lanes per row, strided reads, butterfly merge with lane-unique sentinels.
__global__ void k_sel(const unsigned* __restrict__ bufg, const unsigned* __restrict__ cnt,
                      unsigned capc, unsigned* __restrict__ dd, unsigned* __restrict__ gg) {
    const int w = threadIdx.x >> 6, lane = threadIdx.x & 63;
    const int l15 = lane & 15, lg = lane >> 4;
    const int row = blockIdx.x * 16 + w * 4 + lg;

    const unsigned n = min(cnt[row], capc);
    const unsigned* bp = bufg + (size_t)row * capc;

    unsigned a[9]; unsigned mn = (unsigned)(l15 * 16);
#pragma unroll
    for (int k = 0; k < 9; ++k) a[k] = (unsigned)(l15 * 16 + k);   // lane-unique
    for (unsigned s = l15; s < n; s += 16) top9u(a, mn, bp[s]);
#pragma unroll
    for (int off = 1; off < 16; off <<= 1) {
        unsigned o[9];
#pragma unroll
        for (int k = 0; k < 9; ++k) o[k] = (unsigned)__shfl_xor((int)a[k], off);
#pragma unroll
        for (int k = 0; k < 9; ++k) top9u(a, mn, o[k]);
    }
    const unsigned thr = mn;   // exact 9th-largest key of the row (diag incl.)
    unsigned o = 0;
    for (unsigned s = l15; s < n; s += 16) {
        const unsigned key = bp[s];
        const int col = (int)(key & 16383u);
        if (key >= thr && col != row) { ++o; atomicAdd(&gg[col], 1u); }
    }
#pragma unroll
    for (int off = 1; off < 16; off <<= 1) o += (unsigned)__shfl_xor((int)o, off);
    if (l15 == 0) dd[row] = o;
}

// ---------- 5) wsum = sum_i o*d + g*d - 2o, d = max(o,1) ----------
__global__ void k_wsum(const unsigned* __restrict__ dd, const unsigned* __restrict__ gg,
                       unsigned long long* __restrict__ wsum) {
    const int i = blockIdx.x * 256 + threadIdx.x;
    const unsigned long long o = dd[i];
    const unsigned long long g = gg[i];
    const unsigned long long d = o ? o : 1ull;
    unsigned long long acc = o * d + g * d - 2ull * o;
#pragma unroll
    for (int off = 32; off > 0; off >>= 1) acc += __shfl_xor(acc, off);
    if ((threadIdx.x & 63) == 0 && acc) atomicAdd(wsum, acc);
}

// ---------- 6) finalize ----------
__global__ void k_fin(const unsigned long long* __restrict__ wsum, float* __restrict__ out) {
    out[0] = (float)((double)*wsum * (0.01 / ((double)NR * (double)NR)));
}

extern "C" void kernel_launch(void* const* d_in, const int* in_sizes, int n_in,
                              void* d_out, int out_size, void* d_ws, size_t ws_size,
                              hipStream_t stream) {
    const float* x = (const float*)d_in[0];
    float* out = (float*)d_out;
    char* ws = (char*)d_ws;

    size_t off = 0;
    char* pk = ws + off;                               off += (size_t)NR * DIMS * 2;   // 6.29 MB
    float* thrF = (float*)(ws + off);                  off += (size_t)NR * 4;
    unsigned* cnt = (unsigned*)(ws + off);             off += (size_t)NR * 4;
    unsigned* dd = (unsigned*)(ws + off);              off += (size_t)NR * 4;
    unsigned* gg = (unsigned*)(ws + off);              off += (size_t)NR * 4;
    unsigned long long* wsum = (unsigned long long*)(ws + off); off += 64;
    unsigned* bufg = (unsigned*)(ws + off);
    // per-row survivor capacity from remaining workspace (runtime-constant)
    size_t rem = (ws_size > off) ? (ws_size - off) / ((size_t)NR * 4) : 64;
    unsigned capc = (unsigned)(rem < 64 ? 64 : (rem > 512 ? 512 : rem));

    hipMemsetAsync(cnt, 0, (size_t)NR * 4, stream);
    hipMemsetAsync(gg, 0, (size_t)NR * 4, stream);
    hipMemsetAsync(wsum, 0, 8, stream);

    k_normpack<<<NR / 4, 256, 0, stream>>>(x, pk);
    k_thrS<<<NR / 16, 256, 0, stream>>>(pk, thrF);
    k_mainL<<<(NR / 64) * NCH, 512, 0, stream>>>(pk, thrF, bufg, cnt, capc);
    k_sel<<<NR / 16, 256, 0, stream>>>(bufg, cnt, capc, dd, gg);
    k_wsum<<<NR / 256, 256, 0, stream>>>(dd, gg, wsum);
    k_fin<<<1, 1, 0, stream>>>(wsum, out);
}

// Round 11
// 284.367 us; speedup vs baseline: 1.2987x; 1.2987x over previous
//
#include <hip/hip_runtime.h>
#include <hip/hip_bf16.h>

#define NR 12288
#define DIMS 256
#define NT 192              // number of 64-row tiles
#define SMP 1536            // threshold sample width per row
#define PKT 32768           // bytes per packed 64-row tile
#define HKB 16384           // half-K tile bytes (64 rows x 128 K)

typedef __attribute__((ext_vector_type(8))) short short8v;
typedef __attribute__((ext_vector_type(4))) float f32x4;

__device__ __forceinline__ unsigned short f2bf(float f) {
    unsigned int u = __float_as_uint(f);
    u += 0x7fffu + ((u >> 16) & 1u);
    return (unsigned short)(u >> 16);
}

// Sortable key: top 18 bits = monotone-mapped float, low 14 = col (unique).
__device__ __forceinline__ unsigned packkey(float v, int col) {
    unsigned u = __float_as_uint(v);
    u ^= (unsigned)((int)u >> 31) | 0x80000000u;
    return (u & 0xFFFFC000u) | (unsigned)col;
}

// Keep 9 largest keys; sentinels lane-unique before cross-lane merges (r7 lesson).
__device__ __forceinline__ void top9u(unsigned (&a)[9], unsigned& mn, unsigned key) {
    if (key > mn) {
#pragma unroll
        for (int k = 0; k < 9; ++k) a[k] = (a[k] == mn) ? key : a[k];
        unsigned m = a[0];
#pragma unroll
        for (int k = 1; k < 9; ++k) m = min(m, a[k]);
        mn = m;
    }
}

// async global->LDS DMA, 16B/lane (dest = wave-uniform base + lane*16)
__device__ __forceinline__ void gld16(const void* g, void* l) {
    __builtin_amdgcn_global_load_lds(
        (const __attribute__((address_space(1))) void*)g,
        (__attribute__((address_space(3))) void*)l, 16, 0, 0);
}

// ---------- 1) normalize fp32 -> bf16 into packed fragment layout ----------
// frag addr of (row C, kk, lg): (C>>6)*PKT + kk*4096 + (C&63)*64 + lg*16
__global__ void k_normpack(const float* __restrict__ x, char* __restrict__ pk) {
    const int wave = threadIdx.x >> 6, lane = threadIdx.x & 63;
    const int row = blockIdx.x * 4 + wave;
    const float4 v = *(const float4*)(x + (size_t)row * DIMS + lane * 4);
    float ss = v.x * v.x + v.y * v.y + v.z * v.z + v.w * v.w;
#pragma unroll
    for (int off = 32; off > 0; off >>= 1) ss += __shfl_xor(ss, off);
    const float inv = 1.0f / fmaxf(sqrtf(ss), 1e-12f);
    ushort4 o;
    o.x = f2bf(v.x * inv); o.y = f2bf(v.y * inv);
    o.z = f2bf(v.z * inv); o.w = f2bf(v.w * inv);
    const int kk = lane >> 3, lg = (lane >> 1) & 3, sub = (lane & 1) * 8;
    *(ushort4*)(pk + (size_t)(row >> 6) * PKT + kk * 4096 + (row & 63) * 64 + lg * 16 + sub) = o;
}

// ---------- 2) k_thrS: per-row lower-bound threshold from a 1536-col sample --
__global__ __launch_bounds__(256, 4) void k_thrS(const char* __restrict__ pk,
                                                 float* __restrict__ thrF) {
    const int bid = blockIdx.x;
    const int w = threadIdx.x >> 6, lane = threadIdx.x & 63;
    const int l15 = lane & 15, lg = lane >> 4;
    const int R = bid * 16;
    const int base = (bid & 7) * SMP + w * 384;

    short8v aF[8];
    {
        const char* ap = pk + (size_t)(R >> 6) * PKT + ((R & 63) + l15) * 64 + lg * 16;
#pragma unroll
        for (int kk = 0; kk < 8; ++kk) aF[kk] = *(const short8v*)(ap + kk * 4096);
    }
    unsigned t9[4][9]; unsigned kmin[4];
#pragma unroll
    for (int r = 0; r < 4; ++r) {
        kmin[r] = (unsigned)(lane * 16);
#pragma unroll
        for (int k = 0; k < 9; ++k) t9[r][k] = (unsigned)(lane * 16 + k);   // lane-unique
    }

    for (int t = 0; t < 6; ++t) {
        const int cb = base + t * 64;
        const char* tb = pk + (size_t)(cb >> 6) * PKT + l15 * 64 + lg * 16;
        f32x4 acc0 = {0.f,0.f,0.f,0.f}, acc1 = {0.f,0.f,0.f,0.f};
        f32x4 acc2 = {0.f,0.f,0.f,0.f}, acc3 = {0.f,0.f,0.f,0.f};
#pragma unroll
        for (int kk = 0; kk < 8; ++kk) {
            short8v b0 = *(const short8v*)(tb + kk * 4096);
            short8v b1 = *(const short8v*)(tb + kk * 4096 + 1024);
            short8v b2 = *(const short8v*)(tb + kk * 4096 + 2048);
            short8v b3 = *(const short8v*)(tb + kk * 4096 + 3072);
            acc0 = __builtin_amdgcn_mfma_f32_16x16x32_bf16(aF[kk], b0, acc0, 0,0,0);
            acc1 = __builtin_amdgcn_mfma_f32_16x16x32_bf16(aF[kk], b1, acc1, 0,0,0);
            acc2 = __builtin_amdgcn_mfma_f32_16x16x32_bf16(aF[kk], b2, acc2, 0,0,0);
            acc3 = __builtin_amdgcn_mfma_f32_16x16x32_bf16(aF[kk], b3, acc3, 0,0,0);
        }
        const int c0 = cb + l15;
#pragma unroll
        for (int r = 0; r < 4; ++r) {
            top9u(t9[r], kmin[r], packkey(acc0[r], c0));
            top9u(t9[r], kmin[r], packkey(acc1[r], c0 + 16));
            top9u(t9[r], kmin[r], packkey(acc2[r], c0 + 32));
            top9u(t9[r], kmin[r], packkey(acc3[r], c0 + 48));
        }
    }

#pragma unroll
    for (int off = 1; off < 16; off <<= 1) {
#pragma unroll
        for (int r = 0; r < 4; ++r) {
            unsigned o[9];
#pragma unroll
            for (int k = 0; k < 9; ++k) o[k] = (unsigned)__shfl_xor((int)t9[r][k], off);
#pragma unroll
            for (int k = 0; k < 9; ++k) top9u(t9[r], kmin[r], o[k]);
        }
    }
    __shared__ unsigned m9[4][16][9];
    if (l15 == 0) {
#pragma unroll
        for (int r = 0; r < 4; ++r)
#pragma unroll
            for (int k = 0; k < 9; ++k) m9[w][lg * 4 + r][k] = t9[r][k];
    }
    __syncthreads();
    if (threadIdx.x < 16) {
        unsigned a[9]; unsigned mn = 0;
#pragma unroll
        for (int k = 0; k < 9; ++k) a[k] = (unsigned)k;   // serial: distinct ok
        for (int ww = 0; ww < 4; ++ww)
#pragma unroll
            for (int k = 0; k < 9; ++k) top9u(a, mn, m9[ww][threadIdx.x][k]);
        // float with key-floor == mn's quantum: (v >= tF) <=> key18(v) >= mn&~0x3FFF
        const unsigned T = mn & 0xFFFFC000u;
        thrF[R + threadIdx.x] = (T & 0x80000000u) ? __uint_as_float(T ^ 0x80000000u)
                                                  : __uint_as_float(~T);
    }
}

// ---------- 3) k_mainS: SYMMETRIC half-GEMM, LDS-DMA staged, dual filter ----
// Block (I, s): row-tile I vs J-tiles {I+s, I+s+8, ...} (upper triangle,
// stride-8 for XCD balance). Each sim value v=sim[i,j] is tested twice:
// row-test (v>=thrF[i] -> append (v,j) to row i) and col-test (v>=thrF[j] ->
// append (v,i) to row j); diagonal tile row-test only. MFMA dot is bitwise
// commutative -> consistent with k_thrS regardless of orientation.
// 4 waves rows-split (aF=32 VGPR, proven-resident zone ~85 regs).
__global__ __launch_bounds__(256, 4) void k_mainS(const char* __restrict__ pk,
                                                  const float* __restrict__ thrF,
                                                  unsigned* __restrict__ bufg,
                                                  unsigned* __restrict__ cnt,
                                                  unsigned capc) {
    const int I = blockIdx.x >> 3, s = blockIdx.x & 7;
    const int first = I + s;
    if (first >= NT) return;
    const int M = (NT - 1 - first) / 8 + 1;       // J-tile count
    const int w = threadIdx.x >> 6, lane = threadIdx.x & 63;
    const int l15 = lane & 15, lg = lane >> 4;
    const int iRow = I * 64 + w * 16 + lg * 4;    // +r

    __shared__ __align__(1024) char sb0[HKB];
    __shared__ __align__(1024) char sb1[HKB];

    short8v aF[8];
    {
        const char* ap = pk + (size_t)I * PKT + (w * 16 + l15) * 64 + lg * 16;
#pragma unroll
        for (int kk = 0; kk < 8; ++kk) aF[kk] = *(const short8v*)(ap + kk * 4096);
    }
    float tvI[4];
#pragma unroll
    for (int r = 0; r < 4; ++r) tvI[r] = thrF[iRow + r];

#define STAGE(JT, H, SB)                                                       \
    {                                                                          \
        const char* g_ = pk + (size_t)(JT) * PKT + (H) * HKB + w * 4096 + lane * 16; \
        char* d_ = (SB) + w * 4096;                                            \
        gld16(g_,        d_);                                                  \
        gld16(g_ + 1024, d_ + 1024);                                           \
        gld16(g_ + 2048, d_ + 2048);                                           \
        gld16(g_ + 3072, d_ + 3072);                                           \
    }

#define EPI(CF, ACC)                                                           \
    {                                                                          \
        const int col = Jb + (CF) * 16 + l15;                                  \
        const float tvJ = thrF[col];                                           \
        _Pragma("unroll")                                                      \
        for (int r = 0; r < 4; ++r) {                                          \
            const float v = ACC[r];                                            \
            if (v >= tvI[r]) {                                                 \
                const unsigned key = packkey(v, col);                          \
                const unsigned idx = atomicAdd(&cnt[iRow + r], 1u);            \
                if (idx < capc) bufg[(size_t)(iRow + r) * capc + idx] = key;   \
            }                                                                  \
            if (ndiag && v >= tvJ) {                                           \
                const unsigned key = packkey(v, iRow + r);                     \
                const unsigned idx = atomicAdd(&cnt[col], 1u);                 \
                if (idx < capc) bufg[(size_t)col * capc + idx] = key;          \
            }                                                                  \
        }                                                                      \
    }

    char* cur = sb0; char* nxt = sb1;
    STAGE(first, 0, cur)
    __syncthreads();

    f32x4 acc0, acc1, acc2, acc3;
    const int units = 2 * M;
    for (int u = 0; u < units; ++u) {
        const int Jt = first + 8 * (u >> 1);
        if (u + 1 < units) STAGE(first + 8 * ((u + 1) >> 1), (u + 1) & 1, nxt)
        if ((u & 1) == 0) {
            acc0 = {0.f,0.f,0.f,0.f}; acc1 = {0.f,0.f,0.f,0.f};
            acc2 = {0.f,0.f,0.f,0.f}; acc3 = {0.f,0.f,0.f,0.f};
#pragma unroll
            for (int kkl = 0; kkl < 4; ++kkl) {      // K 0..127
                const char* lb = cur + kkl * 4096 + l15 * 64 + lg * 16;
                short8v b0 = *(const short8v*)(lb);
                short8v b1 = *(const short8v*)(lb + 1024);
                short8v b2 = *(const short8v*)(lb + 2048);
                short8v b3 = *(const short8v*)(lb + 3072);
                acc0 = __builtin_amdgcn_mfma_f32_16x16x32_bf16(aF[kkl], b0, acc0, 0,0,0);
                acc1 = __builtin_amdgcn_mfma_f32_16x16x32_bf16(aF[kkl], b1, acc1, 0,0,0);
                acc2 = __builtin_amdgcn_mfma_f32_16x16x32_bf16(aF[kkl], b2, acc2, 0,0,0);
                acc3 = __builtin_amdgcn_mfma_f32_16x16x32_bf16(aF[kkl], b3, acc3, 0,0,0);
            }
        } else {
#pragma unroll
            for (int kkl = 0; kkl < 4; ++kkl) {      // K 128..255
                const char* lb = cur + kkl * 4096 + l15 * 64 + lg * 16;
                short8v b0 = *(const short8v*)(lb);
                short8v b1 = *(const short8v*)(lb + 1024);
                short8v b2 = *(const short8v*)(lb + 2048);
                short8v b3 = *(const short8v*)(lb + 3072);
                acc0 = __builtin_amdgcn_mfma_f32_16x16x32_bf16(aF[4+kkl], b0, acc0, 0,0,0);
                acc1 = __builtin_amdgcn_mfma_f32_16x16x32_bf16(aF[4+kkl], b1, acc1, 0,0,0);
                acc2 = __builtin_amdgcn_mfma_f32_16x16x32_bf16(aF[4+kkl], b2, acc2, 0,0,0);
                acc3 = __builtin_amdgcn_mfma_f32_16x16x32_bf16(aF[4+kkl], b3, acc3, 0,0,0);
            }
            const int Jb = Jt * 64;
            const bool ndiag = (Jt != I);
            EPI(0, acc0) EPI(1, acc1) EPI(2, acc2) EPI(3, acc3)
        }
        __syncthreads();
        char* t_ = cur; cur = nxt; nxt = t_;
    }
#undef EPI
#undef STAGE
}

// ---------- 4) k_sel: exact per-row 9th key over survivors + degrees ----------
__global__ void k_sel(const unsigned* __restrict__ bufg, const unsigned* __restrict__ cnt,
                      unsigned capc, unsigned* __restrict__ dd, unsigned* __restrict__ gg) {
    const int w = threadIdx.x >> 6, lane = threadIdx.x & 63;
    const int l15 = lane & 15, lg = lane >> 4;
    const int row = blockIdx.x * 16 + w * 4 + lg;

    const unsigned n = min(cnt[row], capc);
    const unsigned* bp = bufg + (size_t)row * capc;

    unsigned a[9]; unsigned mn = (unsigned)(l15 * 16);
#pragma unroll
    for (int k = 0; k < 9; ++k) a[k] = (unsigned)(l15 * 16 + k);   // lane-unique
    for (unsigned t = l15; t < n; t += 16) top9u(a, mn, bp[t]);
#pragma unroll
    for (int off = 1; off < 16; off <<= 1) {
        unsigned o[9];
#pragma unroll
        for (int k = 0; k < 9; ++k) o[k] = (unsigned)__shfl_xor((int)a[k], off);
#pragma unroll
        for (int k = 0; k < 9; ++k) top9u(a, mn, o[k]);
    }
    const unsigned thr = mn;   // exact 9th-largest key of the row (diag incl.)
    unsigned o = 0;
    for (unsigned t = l15; t < n; t += 16) {
        const unsigned key = bp[t];
        const int col = (int)(key & 16383u);
        if (key >= thr && col != row) { ++o; atomicAdd(&gg[col], 1u); }
    }
#pragma unroll
    for (int off = 1; off < 16; off <<= 1) o += (unsigned)__shfl_xor((int)o, off);
    if (l15 == 0) dd[row] = o;
}

// ---------- 5) wsum = sum_i o*d + g*d - 2o, d = max(o,1) ----------
__global__ void k_wsum(const unsigned* __restrict__ dd, const unsigned* __restrict__ gg,
                       unsigned long long* __restrict__ wsum) {
    const int i = blockIdx.x * 256 + threadIdx.x;
    const unsigned long long o = dd[i];
    const unsigned long long g = gg[i];
    const unsigned long long d = o ? o : 1ull;
    unsigned long long acc = o * d + g * d - 2ull * o;
#pragma unroll
    for (int off = 32; off > 0; off >>= 1) acc += __shfl_xor(acc, off);
    if ((threadIdx.x & 63) == 0 && acc) atomicAdd(wsum, acc);
}

// ---------- 6) finalize ----------
__global__ void k_fin(const unsigned long long* __restrict__ wsum, float* __restrict__ out) {
    out[0] = (float)((double)*wsum * (0.01 / ((double)NR * (double)NR)));
}

extern "C" void kernel_launch(void* const* d_in, const int* in_sizes, int n_in,
                              void* d_out, int out_size, void* d_ws, size_t ws_size,
                              hipStream_t stream) {
    const float* x = (const float*)d_in[0];
    float* out = (float*)d_out;
    char* ws = (char*)d_ws;

    size_t off = 0;
    char* pk = ws + off;                               off += (size_t)NR * DIMS * 2;   // 6.29 MB
    float* thrF = (float*)(ws + off);                  off += (size_t)NR * 4;
    unsigned* cnt = (unsigned*)(ws + off);             off += (size_t)NR * 4;
    unsigned* dd = (unsigned*)(ws + off);              off += (size_t)NR * 4;
    unsigned* gg = (unsigned*)(ws + off);              off += (size_t)NR * 4;
    unsigned long long* wsum = (unsigned long long*)(ws + off); off += 64;
    unsigned* bufg = (unsigned*)(ws + off);
    size_t rem = (ws_size > off) ? (ws_size - off) / ((size_t)NR * 4) : 64;
    unsigned capc = (unsigned)(rem < 64 ? 64 : (rem > 512 ? 512 : rem));

    hipMemsetAsync(cnt, 0, (size_t)NR * 4, stream);
    hipMemsetAsync(gg, 0, (size_t)NR * 4, stream);
    hipMemsetAsync(wsum, 0, 8, stream);

    k_normpack<<<NR / 4, 256, 0, stream>>>(x, pk);
    k_thrS<<<NR / 16, 256, 0, stream>>>(pk, thrF);
    k_mainS<<<NT * 8, 256, 0, stream>>>(pk, thrF, bufg, cnt, capc);
    k_sel<<<NR / 16, 256, 0, stream>>>(bufg, cnt, capc, dd, gg);
    k_wsum<<<NR / 256, 256, 0, stream>>>(dd, gg, wsum);
    k_fin<<<1, 1, 0, stream>>>(wsum, out);
}

// Round 12
// 282.761 us; speedup vs baseline: 1.3061x; 1.0057x over previous
//
#include <hip/hip_runtime.h>
#include <hip/hip_bf16.h>

#define NR 12288
#define DIMS 256
#define NT 192              // number of 64-row tiles
#define SMP 1536            // threshold sample width per row
#define PKT 32768           // bytes per packed 64-row tile
#define HKB 16384           // half-K tile bytes (64 rows x 128 K)

typedef __attribute__((ext_vector_type(8))) short short8v;
typedef __attribute__((ext_vector_type(4))) float f32x4;

__device__ __forceinline__ unsigned short f2bf(float f) {
    unsigned int u = __float_as_uint(f);
    u += 0x7fffu + ((u >> 16) & 1u);
    return (unsigned short)(u >> 16);
}

// Sortable key: top 18 bits = monotone-mapped float, low 14 = col (unique).
__device__ __forceinline__ unsigned packkey(float v, int col) {
    unsigned u = __float_as_uint(v);
    u ^= (unsigned)((int)u >> 31) | 0x80000000u;
    return (u & 0xFFFFC000u) | (unsigned)col;
}

// Keep 9 largest keys; sentinels lane-unique before cross-lane merges (r7 lesson).
__device__ __forceinline__ void top9u(unsigned (&a)[9], unsigned& mn, unsigned key) {
    if (key > mn) {
#pragma unroll
        for (int k = 0; k < 9; ++k) a[k] = (a[k] == mn) ? key : a[k];
        unsigned m = a[0];
#pragma unroll
        for (int k = 1; k < 9; ++k) m = min(m, a[k]);
        mn = m;
    }
}

// ---------- 1) normalize fp32 -> bf16 into packed fragment layout ----------
// frag addr of (row C, kk, lg): (C>>6)*PKT + kk*4096 + (C&63)*64 + lg*16
__global__ void k_normpack(const float* __restrict__ x, char* __restrict__ pk) {
    const int wave = threadIdx.x >> 6, lane = threadIdx.x & 63;
    const int row = blockIdx.x * 4 + wave;
    const float4 v = *(const float4*)(x + (size_t)row * DIMS + lane * 4);
    float ss = v.x * v.x + v.y * v.y + v.z * v.z + v.w * v.w;
#pragma unroll
    for (int off = 32; off > 0; off >>= 1) ss += __shfl_xor(ss, off);
    const float inv = 1.0f / fmaxf(sqrtf(ss), 1e-12f);
    ushort4 o;
    o.x = f2bf(v.x * inv); o.y = f2bf(v.y * inv);
    o.z = f2bf(v.z * inv); o.w = f2bf(v.w * inv);
    const int kk = lane >> 3, lg = (lane >> 1) & 3, sub = (lane & 1) * 8;
    *(ushort4*)(pk + (size_t)(row >> 6) * PKT + kk * 4096 + (row & 63) * 64 + lg * 16 + sub) = o;
}

// ---------- 2) k_thrS: per-row lower-bound threshold from a 1536-col sample --
__global__ __launch_bounds__(256, 4) void k_thrS(const char* __restrict__ pk,
                                                 float* __restrict__ thrF) {
    const int bid = blockIdx.x;
    const int w = threadIdx.x >> 6, lane = threadIdx.x & 63;
    const int l15 = lane & 15, lg = lane >> 4;
    const int R = bid * 16;
    const int base = (bid & 7) * SMP + w * 384;

    short8v aF[8];
    {
        const char* ap = pk + (size_t)(R >> 6) * PKT + ((R & 63) + l15) * 64 + lg * 16;
#pragma unroll
        for (int kk = 0; kk < 8; ++kk) aF[kk] = *(const short8v*)(ap + kk * 4096);
    }
    unsigned t9[4][9]; unsigned kmin[4];
#pragma unroll
    for (int r = 0; r < 4; ++r) {
        kmin[r] = (unsigned)(lane * 16);
#pragma unroll
        for (int k = 0; k < 9; ++k) t9[r][k] = (unsigned)(lane * 16 + k);   // lane-unique
    }

    for (int t = 0; t < 6; ++t) {
        const int cb = base + t * 64;
        const char* tb = pk + (size_t)(cb >> 6) * PKT + l15 * 64 + lg * 16;
        f32x4 acc0 = {0.f,0.f,0.f,0.f}, acc1 = {0.f,0.f,0.f,0.f};
        f32x4 acc2 = {0.f,0.f,0.f,0.f}, acc3 = {0.f,0.f,0.f,0.f};
#pragma unroll
        for (int kk = 0; kk < 8; ++kk) {
            short8v b0 = *(const short8v*)(tb + kk * 4096);
            short8v b1 = *(const short8v*)(tb + kk * 4096 + 1024);
            short8v b2 = *(const short8v*)(tb + kk * 4096 + 2048);
            short8v b3 = *(const short8v*)(tb + kk * 4096 + 3072);
            acc0 = __builtin_amdgcn_mfma_f32_16x16x32_bf16(aF[kk], b0, acc0, 0,0,0);
            acc1 = __builtin_amdgcn_mfma_f32_16x16x32_bf16(aF[kk], b1, acc1, 0,0,0);
            acc2 = __builtin_amdgcn_mfma_f32_16x16x32_bf16(aF[kk], b2, acc2, 0,0,0);
            acc3 = __builtin_amdgcn_mfma_f32_16x16x32_bf16(aF[kk], b3, acc3, 0,0,0);
        }
        const int c0 = cb + l15;
#pragma unroll
        for (int r = 0; r < 4; ++r) {
            top9u(t9[r], kmin[r], packkey(acc0[r], c0));
            top9u(t9[r], kmin[r], packkey(acc1[r], c0 + 16));
            top9u(t9[r], kmin[r], packkey(acc2[r], c0 + 32));
            top9u(t9[r], kmin[r], packkey(acc3[r], c0 + 48));
        }
    }

#pragma unroll
    for (int off = 1; off < 16; off <<= 1) {
#pragma unroll
        for (int r = 0; r < 4; ++r) {
            unsigned o[9];
#pragma unroll
            for (int k = 0; k < 9; ++k) o[k] = (unsigned)__shfl_xor((int)t9[r][k], off);
#pragma unroll
            for (int k = 0; k < 9; ++k) top9u(t9[r], kmin[r], o[k]);
        }
    }
    __shared__ unsigned m9[4][16][9];
    if (l15 == 0) {
#pragma unroll
        for (int r = 0; r < 4; ++r)
#pragma unroll
            for (int k = 0; k < 9; ++k) m9[w][lg * 4 + r][k] = t9[r][k];
    }
    __syncthreads();
    if (threadIdx.x < 16) {
        unsigned a[9]; unsigned mn = 0;
#pragma unroll
        for (int k = 0; k < 9; ++k) a[k] = (unsigned)k;   // serial: distinct ok
        for (int ww = 0; ww < 4; ++ww)
#pragma unroll
            for (int k = 0; k < 9; ++k) top9u(a, mn, m9[ww][threadIdx.x][k]);
        // float with key-floor == mn's quantum: (v >= tF) <=> key18(v) >= mn&~0x3FFF
        const unsigned T = mn & 0xFFFFC000u;
        thrF[R + threadIdx.x] = (T & 0x80000000u) ? __uint_as_float(T ^ 0x80000000u)
                                                  : __uint_as_float(~T);
    }
}

// ---------- 3) k_mainS2: symmetric half-GEMM, REG-STAGED LDS (round-6 style) -
// Identical geometry/filter to round-11 k_mainS; only the staging mechanism
// changed: global->reg loads issued at unit top, ds_write after compute,
// before the barrier (T14: latency hides under the MFMA phase). Round-11
// lesson: global_load_lds + __syncthreads drains vmcnt(0) -> 2.4x/unit cost.
__global__ __launch_bounds__(256, 2) void k_mainS2(const char* __restrict__ pk,
                                                   const float* __restrict__ thrF,
                                                   unsigned* __restrict__ bufg,
                                                   unsigned* __restrict__ cnt,
                                                   unsigned capc) {
    const int I = blockIdx.x >> 3, s = blockIdx.x & 7;
    const int first = I + s;
    if (first >= NT) return;
    const int M = (NT - 1 - first) / 8 + 1;       // J-tile count
    const int w = threadIdx.x >> 6, lane = threadIdx.x & 63;
    const int l15 = lane & 15, lg = lane >> 4;
    const int iRow = I * 64 + w * 16 + lg * 4;    // +r

    __shared__ __align__(1024) char sb0[HKB];
    __shared__ __align__(1024) char sb1[HKB];

    short8v aF[8];
    {
        const char* ap = pk + (size_t)I * PKT + (w * 16 + l15) * 64 + lg * 16;
#pragma unroll
        for (int kk = 0; kk < 8; ++kk) aF[kk] = *(const short8v*)(ap + kk * 4096);
    }
    float tvI[4];
#pragma unroll
    for (int r = 0; r < 4; ++r) tvI[r] = thrF[iRow + r];

    uint4 g0, g1, g2, g3;

#define LOADR(JT, H)                                                           \
    {                                                                          \
        const char* g_ = pk + (size_t)(JT) * PKT + (size_t)(H) * HKB + threadIdx.x * 16; \
        g0 = *(const uint4*)(g_);                                              \
        g1 = *(const uint4*)(g_ + 4096);                                       \
        g2 = *(const uint4*)(g_ + 8192);                                       \
        g3 = *(const uint4*)(g_ + 12288);                                      \
    }

#define WRITER(SB)                                                             \
    {                                                                          \
        char* d_ = (SB) + threadIdx.x * 16;                                    \
        *(uint4*)(d_)         = g0;                                            \
        *(uint4*)(d_ + 4096)  = g1;                                            \
        *(uint4*)(d_ + 8192)  = g2;                                            \
        *(uint4*)(d_ + 12288) = g3;                                            \
    }

#define EPI(CF, ACC)                                                           \
    {                                                                          \
        const int col = Jb + (CF) * 16 + l15;                                  \
        const float tvJ = __shfl(tvJl, (CF) * 16 + l15);                       \
        _Pragma("unroll")                                                      \
        for (int r = 0; r < 4; ++r) {                                          \
            const float v = ACC[r];                                            \
            if (v >= tvI[r]) {                                                 \
                const unsigned key = packkey(v, col);                          \
                const unsigned idx = atomicAdd(&cnt[iRow + r], 1u);            \
                if (idx < capc) bufg[(size_t)(iRow + r) * capc + idx] = key;   \
            }                                                                  \
            if (ndiag && v >= tvJ) {                                           \
                const unsigned key = packkey(v, iRow + r);                     \
                const unsigned idx = atomicAdd(&cnt[col], 1u);                 \
                if (idx < capc) bufg[(size_t)col * capc + idx] = key;          \
            }                                                                  \
        }                                                                      \
    }

    char* cur = sb0; char* nxt = sb1;
    LOADR(first, 0)
    WRITER(cur)
    __syncthreads();

    f32x4 acc0, acc1, acc2, acc3;
    const int units = 2 * M;
    for (int u = 0; u < units; ++u) {
        const int Jt = first + 8 * (u >> 1);
        const bool odd = (u & 1) != 0;
        if (u + 1 < units) LOADR(first + 8 * ((u + 1) >> 1), (u + 1) & 1)
        float tvJl = 0.0f;
        if (odd) tvJl = thrF[Jt * 64 + lane];     // issued early, consumed in EPI
        if (!odd) {
            acc0 = {0.f,0.f,0.f,0.f}; acc1 = {0.f,0.f,0.f,0.f};
            acc2 = {0.f,0.f,0.f,0.f}; acc3 = {0.f,0.f,0.f,0.f};
#pragma unroll
            for (int kkl = 0; kkl < 4; ++kkl) {      // K 0..127
                const char* lb = cur + kkl * 4096 + l15 * 64 + lg * 16;
                short8v b0 = *(const short8v*)(lb);
                short8v b1 = *(const short8v*)(lb + 1024);
                short8v b2 = *(const short8v*)(lb + 2048);
                short8v b3 = *(const short8v*)(lb + 3072);
                acc0 = __builtin_amdgcn_mfma_f32_16x16x32_bf16(aF[kkl], b0, acc0, 0,0,0);
                acc1 = __builtin_amdgcn_mfma_f32_16x16x32_bf16(aF[kkl], b1, acc1, 0,0,0);
                acc2 = __builtin_amdgcn_mfma_f32_16x16x32_bf16(aF[kkl], b2, acc2, 0,0,0);
                acc3 = __builtin_amdgcn_mfma_f32_16x16x32_bf16(aF[kkl], b3, acc3, 0,0,0);
            }
        } else {
#pragma unroll
            for (int kkl = 0; kkl < 4; ++kkl) {      // K 128..255
                const char* lb = cur + kkl * 4096 + l15 * 64 + lg * 16;
                short8v b0 = *(const short8v*)(lb);
                short8v b1 = *(const short8v*)(lb + 1024);
                short8v b2 = *(const short8v*)(lb + 2048);
                short8v b3 = *(const short8v*)(lb + 3072);
                acc0 = __builtin_amdgcn_mfma_f32_16x16x32_bf16(aF[4+kkl], b0, acc0, 0,0,0);
                acc1 = __builtin_amdgcn_mfma_f32_16x16x32_bf16(aF[4+kkl], b1, acc1, 0,0,0);
                acc2 = __builtin_amdgcn_mfma_f32_16x16x32_bf16(aF[4+kkl], b2, acc2, 0,0,0);
                acc3 = __builtin_amdgcn_mfma_f32_16x16x32_bf16(aF[4+kkl], b3, acc3, 0,0,0);
            }
            const int Jb = Jt * 64;
            const bool ndiag = (Jt != I);
            EPI(0, acc0) EPI(1, acc1) EPI(2, acc2) EPI(3, acc3)
        }
        if (u + 1 < units) WRITER(nxt)
        __syncthreads();
        char* t_ = cur; cur = nxt; nxt = t_;
    }
#undef EPI
#undef WRITER
#undef LOADR
}

// ---------- 4) k_sel: exact per-row 9th key over survivors + degrees ----------
__global__ void k_sel(const unsigned* __restrict__ bufg, const unsigned* __restrict__ cnt,
                      unsigned capc, unsigned* __restrict__ dd, unsigned* __restrict__ gg) {
    const int w = threadIdx.x >> 6, lane = threadIdx.x & 63;
    const int l15 = lane & 15, lg = lane >> 4;
    const int row = blockIdx.x * 16 + w * 4 + lg;

    const unsigned n = min(cnt[row], capc);
    const unsigned* bp = bufg + (size_t)row * capc;

    unsigned a[9]; unsigned mn = (unsigned)(l15 * 16);
#pragma unroll
    for (int k = 0; k < 9; ++k) a[k] = (unsigned)(l15 * 16 + k);   // lane-unique
    for (unsigned t = l15; t < n; t += 16) top9u(a, mn, bp[t]);
#pragma unroll
    for (int off = 1; off < 16; off <<= 1) {
        unsigned o[9];
#pragma unroll
        for (int k = 0; k < 9; ++k) o[k] = (unsigned)__shfl_xor((int)a[k], off);
#pragma unroll
        for (int k = 0; k < 9; ++k) top9u(a, mn, o[k]);
    }
    const unsigned thr = mn;   // exact 9th-largest key of the row (diag incl.)
    unsigned o = 0;
    for (unsigned t = l15; t < n; t += 16) {
        const unsigned key = bp[t];
        const int col = (int)(key & 16383u);
        if (key >= thr && col != row) { ++o; atomicAdd(&gg[col], 1u); }
    }
#pragma unroll
    for (int off = 1; off < 16; off <<= 1) o += (unsigned)__shfl_xor((int)o, off);
    if (l15 == 0) dd[row] = o;
}

// ---------- 5) wsum = sum_i o*d + g*d - 2o, d = max(o,1) ----------
__global__ void k_wsum(const unsigned* __restrict__ dd, const unsigned* __restrict__ gg,
                       unsigned long long* __restrict__ wsum) {
    const int i = blockIdx.x * 256 + threadIdx.x;
    const unsigned long long o = dd[i];
    const unsigned long long g = gg[i];
    const unsigned long long d = o ? o : 1ull;
    unsigned long long acc = o * d + g * d - 2ull * o;
#pragma unroll
    for (int off = 32; off > 0; off >>= 1) acc += __shfl_xor(acc, off);
    if ((threadIdx.x & 63) == 0 && acc) atomicAdd(wsum, acc);
}

// ---------- 6) finalize ----------
__global__ void k_fin(const unsigned long long* __restrict__ wsum, float* __restrict__ out) {
    out[0] = (float)((double)*wsum * (0.01 / ((double)NR * (double)NR)));
}

extern "C" void kernel_launch(void* const* d_in, const int* in_sizes, int n_in,
                              void* d_out, int out_size, void* d_ws, size_t ws_size,
                              hipStream_t stream) {
    const float* x = (const float*)d_in[0];
    float* out = (float*)d_out;
    char* ws = (char*)d_ws;

    size_t off = 0;
    char* pk = ws + off;                               off += (size_t)NR * DIMS * 2;   // 6.29 MB
    float* thrF = (float*)(ws + off);                  off += (size_t)NR * 4;
    unsigned* cnt = (unsigned*)(ws + off);             off += (size_t)NR * 4;
    unsigned* dd = (unsigned*)(ws + off);              off += (size_t)NR * 4;
    unsigned* gg = (unsigned*)(ws + off);              off += (size_t)NR * 4;
    unsigned long long* wsum = (unsigned long long*)(ws + off); off += 64;
    unsigned* bufg = (unsigned*)(ws + off);
    size_t rem = (ws_size > off) ? (ws_size - off) / ((size_t)NR * 4) : 64;
    unsigned capc = (unsigned)(rem < 64 ? 64 : (rem > 512 ? 512 : rem));

    hipMemsetAsync(cnt, 0, (size_t)NR * 4, stream);
    hipMemsetAsync(gg, 0, (size_t)NR * 4, stream);
    hipMemsetAsync(wsum, 0, 8, stream);

    k_normpack<<<NR / 4, 256, 0, stream>>>(x, pk);
    k_thrS<<<NR / 16, 256, 0, stream>>>(pk, thrF);
    k_mainS2<<<NT * 8, 256, 0, stream>>>(pk, thrF, bufg, cnt, capc);
    k_sel<<<NR / 16, 256, 0, stream>>>(bufg, cnt, capc, dd, gg);
    k_wsum<<<NR / 256, 256, 0, stream>>>(dd, gg, wsum);
    k_fin<<<1, 1, 0, stream>>>(wsum, out);
}